// Round 1
// baseline (802.159 us; speedup 1.0000x reference)
//
#include <hip/hip_runtime.h>
#include <climits>

#define NN 50000
#define EE 1600000
#define DIN 128
#define DOUT 64
#define BN_EPS 1e-5f

__device__ __forceinline__ int f2ord(float f) {
    int i = __float_as_int(f);
    return i >= 0 ? i : (i ^ 0x7fffffff);
}
__device__ __forceinline__ float ord2f(int k) {
    return __int_as_float(k >= 0 ? k : (k ^ 0x7fffffff));
}

// ---------------- K0: init scratch ----------------
__global__ void k0_init(int* m, int* deg, float* s, float* colsum, float* colsq) {
    int i = blockIdx.x * blockDim.x + threadIdx.x;
    if (i < NN) { m[i] = INT_MIN; deg[i] = 0; s[i] = 0.f; }
    if (i < DOUT) { colsum[i] = 0.f; colsq[i] = 0.f; }
}

// ---------------- K1: h = x @ W^T  (+ per-node attention scalars) ----------------
// lane = output col; W row register-resident (128 VGPR / lane)
__global__ void k1_gemm(const float* __restrict__ x, const float* __restrict__ W,
                        const float* __restrict__ ne,
                        const float* __restrict__ atti, const float* __restrict__ attj,
                        const float* __restrict__ atemi, const float* __restrict__ atemj,
                        float* __restrict__ h, float* __restrict__ a_i, float* __restrict__ a_j) {
    const int l = threadIdx.x & 63;
    const int wv = threadIdx.x >> 6;
    const int gw = blockIdx.x * (blockDim.x >> 6) + wv;
    const int nw = gridDim.x * (blockDim.x >> 6);

    float4 w4[32];
    const float4* Wv = (const float4*)(W + l * DIN);
#pragma unroll
    for (int j = 0; j < 32; ++j) w4[j] = Wv[j];

    const float ai_l = atti[l], aj_l = attj[l], emi_l = atemi[l], emj_l = atemj[l];

    for (int n = gw; n < NN; n += nw) {
        const float4* xv = (const float4*)(x + n * DIN);
        float acc = 0.f;
#pragma unroll
        for (int j = 0; j < 32; ++j) {
            float4 xx = xv[j];
            acc += w4[j].x * xx.x + w4[j].y * xx.y + w4[j].z * xx.z + w4[j].w * xx.w;
        }
        float nev = ne[n * DOUT + l];
        float v1 = acc * ai_l + nev * emi_l;
        float v2 = acc * aj_l + nev * emj_l;
#pragma unroll
        for (int d = 32; d >= 1; d >>= 1) {
            v1 += __shfl_xor(v1, d);
            v2 += __shfl_xor(v2, d);
        }
        h[n * DOUT + l] = acc;
        if (l == 0) { a_i[n] = v1; a_j[n] = v2; }
    }
}

// ---------------- K2: per-edge logit -> segment max (ordered-int atomicMax) + degree ----------------
__global__ void k2_edges(const int* __restrict__ ei,
                         const float* __restrict__ a_i, const float* __restrict__ a_j,
                         int* __restrict__ m, int* __restrict__ deg) {
    int tid = blockIdx.x * blockDim.x + threadIdx.x;
    int stride = gridDim.x * blockDim.x;
    for (int e = tid; e < EE; e += stride) {
        int src = ei[e];
        int dst = ei[EE + e];
        float lg = a_i[dst] + a_j[src];
        lg = lg > 0.f ? lg : 0.2f * lg;
        atomicMax(&m[dst], f2ord(lg));
        atomicAdd(&deg[dst], 1);
    }
}

// ---------------- K3: single-block exclusive scan of degrees -> offsets, cursor ----------------
__global__ void __launch_bounds__(1024) k3_scan(const int* __restrict__ deg,
                                                int* __restrict__ offsets, int* __restrict__ cursor) {
    __shared__ int lds[1024];
    const int t = threadIdx.x;
    const int CH = (NN + 1023) / 1024;  // 49
    const int base = t * CH;
    int local = 0;
    for (int i = 0; i < CH; ++i) {
        int idx = base + i;
        if (idx < NN) local += deg[idx];
    }
    lds[t] = local;
    __syncthreads();
    for (int off = 1; off < 1024; off <<= 1) {
        int v = (t >= off) ? lds[t - off] : 0;
        __syncthreads();
        lds[t] += v;
        __syncthreads();
    }
    int run = (t == 0) ? 0 : lds[t - 1];
    for (int i = 0; i < CH; ++i) {
        int idx = base + i;
        if (idx < NN) {
            offsets[idx] = run;
            cursor[idx] = run;
            run += deg[idx];
        }
    }
}

// ---------------- K4: scatter edges into CSR slots; e = exp(logit - m); s += e ----------------
__global__ void k4_scatter(const int* __restrict__ ei,
                           const float* __restrict__ a_i, const float* __restrict__ a_j,
                           const int* __restrict__ m, float* __restrict__ s,
                           int* __restrict__ cursor, int2* __restrict__ csr) {
    int tid = blockIdx.x * blockDim.x + threadIdx.x;
    int stride = gridDim.x * blockDim.x;
    for (int e = tid; e < EE; e += stride) {
        int src = ei[e];
        int dst = ei[EE + e];
        float lg = a_i[dst] + a_j[src];
        lg = lg > 0.f ? lg : 0.2f * lg;
        float ev = expf(lg - ord2f(m[dst]));
        atomicAdd(&s[dst], ev);
        int pos = atomicAdd(&cursor[dst], 1);
        csr[pos] = make_int2(src, __float_as_int(ev));
    }
}

// ---------------- K5: per-node aggregation (wave per node) + BN partial sums ----------------
__global__ void k5_agg(const float* __restrict__ h, const int2* __restrict__ csr,
                       const int* __restrict__ offsets, const int* __restrict__ endv,
                       const float* __restrict__ s, const float* __restrict__ bias,
                       float* __restrict__ out_pre,
                       float* __restrict__ colsum, float* __restrict__ colsq) {
    const int l = threadIdx.x & 63;
    const int wv = threadIdx.x >> 6;
    const int gw = blockIdx.x * (blockDim.x >> 6) + wv;
    const int nw = gridDim.x * (blockDim.x >> 6);
    const float bias_l = bias[l];

    float bsum = 0.f, bsq = 0.f;

    for (int n = gw; n < NN; n += nw) {
        int idx = offsets[n];
        const int end = endv[n];
        float acc = 0.f;
        if (idx < end && (idx & 1)) {  // align to int4 (pairs at even index)
            int2 p = csr[idx];
            acc += __int_as_float(p.y) * h[(p.x << 6) + l];
            ++idx;
        }
        for (; idx + 2 <= end; idx += 2) {
            int4 p = *(const int4*)(&csr[idx]);
            float h0 = h[(p.x << 6) + l];
            float h1 = h[(p.z << 6) + l];
            acc += __int_as_float(p.y) * h0;
            acc += __int_as_float(p.w) * h1;
        }
        if (idx < end) {
            int2 p = csr[idx];
            acc += __int_as_float(p.y) * h[(p.x << 6) + l];
        }
        float outv = acc / (s[n] + 1e-16f) + bias_l;
        out_pre[n * DOUT + l] = outv;
        bsum += outv;
        bsq += outv * outv;
    }

    __shared__ float red[8][64];
    red[wv][l] = bsum;
    red[4 + wv][l] = bsq;
    __syncthreads();
    if (wv == 0) {
        float ts = red[0][l] + red[1][l] + red[2][l] + red[3][l];
        float tq = red[4][l] + red[5][l] + red[6][l] + red[7][l];
        atomicAdd(&colsum[l], ts);
        atomicAdd(&colsq[l], tq);
    }
}

// ---------------- K6: BN coefficients ----------------
__global__ void k6_coef(const float* __restrict__ colsum, const float* __restrict__ colsq,
                        const float* __restrict__ gamma, const float* __restrict__ beta,
                        float* __restrict__ scale, float* __restrict__ shift) {
    int c = threadIdx.x;
    if (c < DOUT) {
        float mean = colsum[c] * (1.f / NN);
        float var = colsq[c] * (1.f / NN) - mean * mean;
        float inv = rsqrtf(var + BN_EPS);
        float sc = gamma[c] * inv;
        scale[c] = sc;
        shift[c] = beta[c] - mean * sc;
    }
}

// ---------------- K7: y = relu(out*scale + shift), vectorized ----------------
__global__ void k7_apply(const float4* __restrict__ out_pre,
                         const float4* __restrict__ scale, const float4* __restrict__ shift,
                         float4* __restrict__ y) {
    const int n4 = NN * DOUT / 4;
    int tid = blockIdx.x * blockDim.x + threadIdx.x;
    int stride = gridDim.x * blockDim.x;
    for (int i = tid; i < n4; i += stride) {
        float4 o = out_pre[i];
        int c = i & 15;
        float4 sc = scale[c], sh = shift[c];
        float4 r;
        r.x = fmaxf(o.x * sc.x + sh.x, 0.f);
        r.y = fmaxf(o.y * sc.y + sh.y, 0.f);
        r.z = fmaxf(o.z * sc.z + sh.z, 0.f);
        r.w = fmaxf(o.w * sc.w + sh.w, 0.f);
        y[i] = r;
    }
}

extern "C" void kernel_launch(void* const* d_in, const int* in_sizes, int n_in,
                              void* d_out, int out_size, void* d_ws, size_t ws_size,
                              hipStream_t stream) {
    const float* x      = (const float*)d_in[0];
    const int*   ei     = (const int*)d_in[1];
    const float* ne     = (const float*)d_in[2];
    const float* W      = (const float*)d_in[3];
    const float* att_i  = (const float*)d_in[4];
    const float* att_j  = (const float*)d_in[5];
    const float* atemi  = (const float*)d_in[6];
    const float* atemj  = (const float*)d_in[7];
    const float* bias   = (const float*)d_in[8];
    const float* gamma  = (const float*)d_in[9];
    const float* beta   = (const float*)d_in[10];
    float* out = (float*)d_out;

    char* w = (char*)d_ws;
    size_t off = 0;
    auto alloc = [&](size_t bytes) -> void* {
        void* p = w + off;
        off = (off + bytes + 255) & ~(size_t)255;
        return p;
    };
    float* h       = (float*)alloc((size_t)NN * DOUT * 4);
    float* out_pre = (float*)alloc((size_t)NN * DOUT * 4);
    int2*  csr     = (int2*)alloc((size_t)EE * 8);
    float* a_i     = (float*)alloc((size_t)NN * 4);
    float* a_j     = (float*)alloc((size_t)NN * 4);
    int*   m       = (int*)alloc((size_t)NN * 4);
    int*   deg     = (int*)alloc((size_t)NN * 4);
    float* s       = (float*)alloc((size_t)NN * 4);
    int*   offsets = (int*)alloc((size_t)NN * 4);
    int*   cursor  = (int*)alloc((size_t)NN * 4);
    float* colsum  = (float*)alloc(DOUT * 4);
    float* colsq   = (float*)alloc(DOUT * 4);
    float* scale   = (float*)alloc(DOUT * 4);
    float* shift   = (float*)alloc(DOUT * 4);

    k0_init<<<(NN + 255) / 256, 256, 0, stream>>>(m, deg, s, colsum, colsq);
    k1_gemm<<<1024, 256, 0, stream>>>(x, W, ne, att_i, att_j, atemi, atemj, h, a_i, a_j);
    k2_edges<<<2048, 256, 0, stream>>>(ei, a_i, a_j, m, deg);
    k3_scan<<<1, 1024, 0, stream>>>(deg, offsets, cursor);
    k4_scatter<<<2048, 256, 0, stream>>>(ei, a_i, a_j, m, s, cursor, csr);
    k5_agg<<<1024, 256, 0, stream>>>(h, csr, offsets, cursor, s, bias, out_pre, colsum, colsq);
    k6_coef<<<1, 64, 0, stream>>>(colsum, colsq, gamma, beta, scale, shift);
    k7_apply<<<1024, 256, 0, stream>>>((const float4*)out_pre, (const float4*)scale,
                                       (const float4*)shift, (float4*)out);
}